// Round 11
// baseline (66.881 us; speedup 1.0000x reference)
//
#include <hip/hip_runtime.h>
#include <hip/hip_bf16.h>
#include <math.h>

#define HH 192
#define WW 192
#define NPIX (HH * WW)
#define SCALE 0.25f          // head_dim(16)^-0.5

// attention tile: 8 rows x 4 cols, all 4 heads; halo 14 x 10 = 140 pixels
#define HLY 14
#define HLX 10
#define NH  (HLY * HLX)      // 140
#define REG2 (NH * 8 + 4)    // 1124 dw; mod 32 = 4 -> head regions stagger
                             // by 4 banks (r7-r10-proven pattern)

typedef __attribute__((ext_vector_type(8))) short bf16x8;
typedef __attribute__((ext_vector_type(4))) float f32x4;

static __device__ __forceinline__ float blo(unsigned int w) { return __uint_as_float(w << 16); }
static __device__ __forceinline__ float bhi(unsigned int w) { return __uint_as_float(w & 0xffff0000u); }

static __device__ __forceinline__ short bf16s(float f)
{
    __hip_bfloat16 h = __float2bfloat16(f);
    short s; __builtin_memcpy(&s, &h, 2); return s;
}

static __device__ __forceinline__ unsigned int pack_bf16(float a, float b)
{
    unsigned short ul = (unsigned short)bf16s(a);
    unsigned short uh = (unsigned short)bf16s(b);
    return ((unsigned int)uh << 16) | ul;
}

// ---------------------------------------------------------------------------
// Kernel 1: Q/K/V projection via MFMA (r8/r10-proven LDS-staged version).
// x [64 cin][NPIX] f32 -> q,k,v bf16-packed [NPIX][32 dw].
// Tail block (blockIdx == NPIX/64) preps wp into wT rows 192..255.
// ---------------------------------------------------------------------------
__global__ __launch_bounds__(256) void qkv_mfma(
    const float* __restrict__ x,
    const float* __restrict__ wq, const float* __restrict__ wk,
    const float* __restrict__ wv, const float* __restrict__ wp,
    unsigned int* __restrict__ qg, unsigned int* __restrict__ kg,
    unsigned int* __restrict__ vg, short* __restrict__ wT)
{
    const int t = threadIdx.x;

    if (blockIdx.x == NPIX / 64) {
        #pragma unroll
        for (int i = 0; i < 16; ++i) {
            const int idx = i * 256 + t;      // 0..4095
            const int n = idx >> 6, k = idx & 63;
            wT[(192 + n) * 64 + k] = bf16s(wp[k * 64 + n]);
        }
        return;
    }

    __shared__ short lds[(64 + 192) * 72];   // xT then wTs
    short* xT = lds;
    short* wTs = lds + 64 * 72;
    const int px0 = blockIdx.x * 64;

    #pragma unroll
    for (int r = 0; r < 16; ++r) {
        const int idx = r * 256 + t;          // 0..4095
        const int cin = idx >> 6, pxl = idx & 63;
        xT[pxl * 72 + cin] = bf16s(x[(size_t)cin * NPIX + px0 + pxl]);
    }
    #pragma unroll
    for (int m = 0; m < 3; ++m) {
        const float* ws = (m == 0) ? wq : (m == 1) ? wk : wv;
        #pragma unroll
        for (int r = 0; r < 16; ++r) {
            const int idx = r * 256 + t;      // 0..4095
            const int k = idx >> 6, n = idx & 63;
            wTs[(m * 64 + n) * 72 + k] = bf16s(ws[k * 64 + n]);
        }
    }
    __syncthreads();

    const int lane = t & 63;
    const int wid  = t >> 6;                  // M-tile (16 px)
    const int l15  = lane & 15;
    const int kg4  = lane >> 4;

    f32x4 acc[12];
    #pragma unroll
    for (int nt = 0; nt < 12; ++nt) acc[nt] = (f32x4){0.f, 0.f, 0.f, 0.f};

    #pragma unroll
    for (int ks = 0; ks < 2; ++ks) {
        const bf16x8 a = *reinterpret_cast<const bf16x8*>(
            &xT[(wid * 16 + l15) * 72 + ks * 32 + kg4 * 8]);
        #pragma unroll
        for (int nt = 0; nt < 12; ++nt) {
            const bf16x8 b = *reinterpret_cast<const bf16x8*>(
                &wTs[(nt * 16 + l15) * 72 + ks * 32 + kg4 * 8]);
            acc[nt] = __builtin_amdgcn_mfma_f32_16x16x32_bf16(a, b, acc[nt], 0, 0, 0);
        }
    }

    #pragma unroll
    for (int nt = 0; nt < 12; ++nt) {
        unsigned int* dst = (nt < 4) ? qg : (nt < 8) ? kg : vg;
        const int dwb = (nt & 3) * 8 + (l15 >> 1);
        #pragma unroll
        for (int r = 0; r < 4; ++r) {
            const float val = acc[nt][r];
            const float par = __shfl_xor(val, 1, 64);
            if (!(lane & 1)) {
                const int opx = px0 + wid * 16 + kg4 * 4 + r;
                dst[(size_t)opx * 32 + dwb] = pack_bf16(val, par);
            }
        }
    }
}

// one neighborhood step: k from LDS, v from GLOBAL (L1/L2-resident),
// dot(q,k)*m -> exp -> accumulate into acc/S
#define NBR_STEP(HIDX, VOFF)                                                  \
    {                                                                         \
        const int hidx_ = (HIDX);                                             \
        const uint4 ka = *reinterpret_cast<const uint4*>(kreg + hidx_ * 8);   \
        const uint4 k2 = *reinterpret_cast<const uint4*>(kreg + hidx_ * 8 + 4);\
        const uint4 va = *reinterpret_cast<const uint4*>(vbase + (VOFF));     \
        const uint4 v2 = *reinterpret_cast<const uint4*>(vbase + (VOFF) + 4); \
        float d0 = qv[0] * blo(ka.x), d1 = qv[1] * bhi(ka.x);                 \
        float d2 = qv[2] * blo(ka.y), d3 = qv[3] * bhi(ka.y);                 \
        d0 = fmaf(qv[4],  blo(ka.z), d0); d1 = fmaf(qv[5],  bhi(ka.z), d1);   \
        d2 = fmaf(qv[6],  blo(ka.w), d2); d3 = fmaf(qv[7],  bhi(ka.w), d3);   \
        d0 = fmaf(qv[8],  blo(k2.x), d0); d1 = fmaf(qv[9],  bhi(k2.x), d1);   \
        d2 = fmaf(qv[10], blo(k2.y), d2); d3 = fmaf(qv[11], bhi(k2.y), d3);   \
        d0 = fmaf(qv[12], blo(k2.z), d0); d1 = fmaf(qv[13], bhi(k2.z), d1);   \
        d2 = fmaf(qv[14], blo(k2.w), d2); d3 = fmaf(qv[15], bhi(k2.w), d3);   \
        const float dot = (d0 + d1) + (d2 + d3);                              \
        const float m = sm[hidx_];                                            \
        const float pf = __expf(SCALE * dot * m);                             \
        S += pf;                                                              \
        const float pm = pf * m;                                              \
        acc[0]  = fmaf(pm, blo(va.x), acc[0]);                                \
        acc[1]  = fmaf(pm, bhi(va.x), acc[1]);                                \
        acc[2]  = fmaf(pm, blo(va.y), acc[2]);                                \
        acc[3]  = fmaf(pm, bhi(va.y), acc[3]);                                \
        acc[4]  = fmaf(pm, blo(va.z), acc[4]);                                \
        acc[5]  = fmaf(pm, bhi(va.z), acc[5]);                                \
        acc[6]  = fmaf(pm, blo(va.w), acc[6]);                                \
        acc[7]  = fmaf(pm, bhi(va.w), acc[7]);                                \
        acc[8]  = fmaf(pm, blo(v2.x), acc[8]);                                \
        acc[9]  = fmaf(pm, bhi(v2.x), acc[9]);                                \
        acc[10] = fmaf(pm, blo(v2.y), acc[10]);                               \
        acc[11] = fmaf(pm, bhi(v2.y), acc[11]);                               \
        acc[12] = fmaf(pm, blo(v2.z), acc[12]);                               \
        acc[13] = fmaf(pm, bhi(v2.z), acc[13]);                               \
        acc[14] = fmaf(pm, blo(v2.w), acc[14]);                               \
        acc[15] = fmaf(pm, bhi(v2.w), acc[15]);                               \
    }

// ---------------------------------------------------------------------------
// Kernel 2: tiled neighborhood attention + fused MFMA output projection.
// Block = 256 thr: 8x4 pixel tile x 4 heads x 2 neighbor-halves; grid 1152,
// XCD-swizzled. ONLY K (+sims) staged in LDS (18.5 KB -> 5 blocks/CU, 20
// waves/CU); V read directly from global (block working set 17.9 KB, L1/L2).
// ---------------------------------------------------------------------------
__global__ __launch_bounds__(256) void attn_proj(
    const unsigned int* __restrict__ qg,
    const unsigned int* __restrict__ kg,
    const unsigned int* __restrict__ vg,
    const float* __restrict__ sims,
    const short* __restrict__ wT,
    float* __restrict__ out)
{
    __shared__ unsigned int smem[4 * REG2 + NH];  // k[4][REG2], sims[140]

    const int bid = blockIdx.x;
    const int tl = (bid & 7) * 144 + (bid >> 3);  // XCD swizzle (1152 = 8*144)
    const int ty = tl / 48, tx = tl - ty * 48;
    const int Y0 = ty * 8, X0 = tx * 4;
    int hy0 = Y0 - 3; hy0 = hy0 < 0 ? 0 : (hy0 > HH - HLY ? HH - HLY : hy0);
    int hx0 = X0 - 3; hx0 = hx0 < 0 ? 0 : (hx0 > WW - HLX ? WW - HLX : hx0);
    const int t = threadIdx.x;

    // ---- stage K halo only: 140 px x 8 uint4 (64 ch) = 1120 units
    #pragma unroll
    for (int i = 0; i < 5; ++i) {
        const int idx = i * 256 + t;
        if (idx < NH * 8) {
            const int hidx = idx >> 3, u = idx & 7;
            const int r = hidx / HLX, c = hidx - r * HLX;
            const int np = (hy0 + r) * WW + hx0 + c;
            const int h = u >> 1, hf = u & 1;
            const uint4 kk = *reinterpret_cast<const uint4*>(kg + (size_t)np * 32 + u * 4);
            *reinterpret_cast<uint4*>(smem + h * REG2 + hidx * 8 + hf * 4) = kk;
        }
    }
    if (t < NH) {
        const int r = t / HLX, c = t - r * HLX;
        const int np = (hy0 + r) * WW + hx0 + c;
        const int sbase = (Y0 >> 4) * 12 + (X0 >> 4);   // block-uniform
        reinterpret_cast<float*>(smem)[4 * REG2 + t] = sims[np * 144 + sbase];
    }
    __syncthreads();

    // ---- attention: thread = (pixel, head, neighbor-half)
    const int half = t & 1, hl = (t >> 1) & 1, p = (t >> 2) & 31, hp = t >> 7;
    const int h = hp * 2 + hl;
    const int py = p >> 2, pxq = p & 3;
    const int y = Y0 + py, xq = X0 + pxq;
    int sy = y - 3;  sy = sy < 0 ? 0 : (sy > HH - 7 ? HH - 7 : sy);
    int sx = xq - 3; sx = sx < 0 ? 0 : (sx > WW - 7 ? WW - 7 : sx);
    const int wbase = (sy - hy0) * HLX + (sx - hx0);
    const unsigned int* vbase = vg + (size_t)(sy * WW + sx) * 32 + h * 8;

    float qv[16];
    {
        const unsigned int* qp = qg + (size_t)(y * WW + xq) * 32 + h * 8;
        const uint4 a = *reinterpret_cast<const uint4*>(qp);
        const uint4 b = *reinterpret_cast<const uint4*>(qp + 4);
        const unsigned int qs[8] = { a.x, a.y, a.z, a.w, b.x, b.y, b.z, b.w };
        #pragma unroll
        for (int e = 0; e < 8; ++e) { qv[2 * e] = blo(qs[e]); qv[2 * e + 1] = bhi(qs[e]); }
    }

    const unsigned int* kreg = smem + h * REG2;
    const float* sm = reinterpret_cast<const float*>(smem + 4 * REG2);

    float S = 0.f;
    float acc[16];
    #pragma unroll
    for (int d = 0; d < 16; ++d) acc[d] = 0.f;

    // neighbors nn = 2*i + half, i = 0..23 unconditional; tail nn=48 (half 0)
    #pragma unroll
    for (int i = 0; i < 24; ++i) {
        const int nn = 2 * i + half;
        const int ky = (nn * 37) >> 8;        // nn/7 for nn<56
        const int kx = nn - 7 * ky;
        NBR_STEP(wbase + ky * HLX + kx, (ky * WW + kx) * 32);
    }
    if (half == 0) {
        NBR_STEP(wbase + 6 * HLX + 6, (6 * WW + 6) * 32);   // nn = 48
    }

    // combine even/odd neighbor halves (adjacent lanes share (p,h))
    const float S2 = S + __shfl_xor(S, 1, 64);
    float lo[8], hi[8];
    #pragma unroll
    for (int j = 0; j < 8; ++j) { lo[j] = acc[j]; hi[j] = acc[8 + j]; }
    #pragma unroll
    for (int j = 0; j < 8; ++j) {
        lo[j] += __shfl_xor(lo[j], 1, 64);
        hi[j] += __shfl_xor(hi[j], 1, 64);
    }
    const float inv = 1.f / S2;
    float o[8];
    #pragma unroll
    for (int j = 0; j < 8; ++j) o[j] = ((half == 0) ? lo[j] : hi[j]) * inv;

    // ---- fused projection: attn-out -> LDS (bf16 A-tile), MFMA with wp
    __syncthreads();                           // all k/sims LDS reads done
    {
        // A_lds: [32 px][72 ch-pad] shorts, overlaps dead k region
        short* A_lds = reinterpret_cast<short*>(smem);
        const uint4 w4 = make_uint4(pack_bf16(o[0], o[1]), pack_bf16(o[2], o[3]),
                                    pack_bf16(o[4], o[5]), pack_bf16(o[6], o[7]));
        *reinterpret_cast<uint4*>(&A_lds[p * 72 + h * 16 + half * 8]) = w4;
    }
    __syncthreads();

    const short* A_lds = reinterpret_cast<const short*>(smem);
    const int lane = t & 63;
    const int w    = t >> 6;                   // wave id
    const int mt   = w & 1;                    // M-tile (16 px)
    const int np2  = w >> 1;                   // N-pair (2 x 16 couts)
    const int l15  = lane & 15;
    const int kg4  = lane >> 4;

    bf16x8 afrag[2];
    #pragma unroll
    for (int ks = 0; ks < 2; ++ks)
        afrag[ks] = *reinterpret_cast<const bf16x8*>(
            &A_lds[(mt * 16 + l15) * 72 + ks * 32 + kg4 * 8]);

    #pragma unroll
    for (int nt2 = 0; nt2 < 2; ++nt2) {
        const int nt = np2 * 2 + nt2;
        const int n = nt * 16 + l15;
        f32x4 pacc = (f32x4){0.f, 0.f, 0.f, 0.f};
        #pragma unroll
        for (int ks = 0; ks < 2; ++ks) {
            const bf16x8 b = *reinterpret_cast<const bf16x8*>(
                &wT[(192 + n) * 64 + ks * 32 + kg4 * 8]);
            pacc = __builtin_amdgcn_mfma_f32_16x16x32_bf16(afrag[ks], b, pacc, 0, 0, 0);
        }
        const int pr = mt * 16 + kg4 * 4;      // 4 consecutive tile pixels
        const int gy = Y0 + (pr >> 2);         // = one tile row
        *reinterpret_cast<float4*>(out + (size_t)n * NPIX + gy * WW + X0) =
            make_float4(pacc[0], pacc[1], pacc[2], pacc[3]);
    }
}

// ---------------------------------------------------------------------------
extern "C" void kernel_launch(void* const* d_in, const int* in_sizes, int n_in,
                              void* d_out, int out_size, void* d_ws, size_t ws_size,
                              hipStream_t stream)
{
    const float* x    = (const float*)d_in[0];
    const float* sims = (const float*)d_in[1];
    const float* wq   = (const float*)d_in[2];
    const float* wk   = (const float*)d_in[3];
    const float* wv   = (const float*)d_in[4];
    const float* wp   = (const float*)d_in[5];
    float* out = (float*)d_out;

    unsigned int* qg = (unsigned int*)d_ws;            // bf16x2 [NPIX][32]
    unsigned int* kg = qg + (size_t)NPIX * 32;
    unsigned int* vg = kg + (size_t)NPIX * 32;
    short* wT = (short*)(vg + (size_t)NPIX * 32);      // bf16 [256][64]

    qkv_mfma<<<NPIX / 64 + 1, 256, 0, stream>>>(x, wq, wk, wv, wp, qg, kg, vg, wT);
    attn_proj<<<1152, 256, 0, stream>>>(qg, kg, vg, sims, wT, out);
}

// Round 12
// 38.483 us; speedup vs baseline: 1.7379x; 1.7379x over previous
//
#include <hip/hip_runtime.h>
#include <math.h>

#define HH 192
#define WW 192
#define NPIX (HH * WW)
#define SCALE 0.25f          // head_dim(16)^-0.5

// attention tile: 8 rows x 4 cols, all 4 heads; halo 14 x 10 = 140 pixels
#define HLY 14
#define HLX 10
#define NH  (HLY * HLX)      // 140
#define REG2 (NH * 8 + 4)    // 1124 dw; mod 32 = 4 -> head regions stagger
                             // by 4 banks (r7-r10-proven pattern)

typedef __attribute__((ext_vector_type(8))) _Float16 f16x8;
typedef __attribute__((ext_vector_type(2))) _Float16 f16x2;
typedef __attribute__((ext_vector_type(4))) float f32x4;

#if __has_builtin(__builtin_amdgcn_fdot2)
#define FDOT2(a, b, c) __builtin_amdgcn_fdot2((a), (b), (c), false)
#else
#define FDOT2(a, b, c) fmaf((float)(a)[0], (float)(b)[0], \
                            fmaf((float)(a)[1], (float)(b)[1], (c)))
#endif

static __device__ __forceinline__ f16x2 u2h(unsigned int u)
{
    f16x2 r; __builtin_memcpy(&r, &u, 4); return r;
}

static __device__ __forceinline__ short f16s(float f)
{
    _Float16 h = (_Float16)f;
    short s; __builtin_memcpy(&s, &h, 2); return s;
}

static __device__ __forceinline__ unsigned int pack_f16(float a, float b)
{
    unsigned short ul = (unsigned short)f16s(a);
    unsigned short uh = (unsigned short)f16s(b);
    return ((unsigned int)uh << 16) | ul;
}

// ---------------------------------------------------------------------------
// Kernel 1: Q/K/V projection via MFMA (r8/r10 structure, f16 pipeline).
// x [64 cin][NPIX] f32 -> q,k,v f16-packed [NPIX][32 dw].
// Tail block (blockIdx == NPIX/64) preps wp into wT rows 192..255 (f16).
// ---------------------------------------------------------------------------
__global__ __launch_bounds__(256) void qkv_mfma(
    const float* __restrict__ x,
    const float* __restrict__ wq, const float* __restrict__ wk,
    const float* __restrict__ wv, const float* __restrict__ wp,
    unsigned int* __restrict__ qg, unsigned int* __restrict__ kg,
    unsigned int* __restrict__ vg, short* __restrict__ wT)
{
    const int t = threadIdx.x;

    if (blockIdx.x == NPIX / 64) {
        #pragma unroll
        for (int i = 0; i < 16; ++i) {
            const int idx = i * 256 + t;      // 0..4095
            const int n = idx >> 6, k = idx & 63;
            wT[(192 + n) * 64 + k] = f16s(wp[k * 64 + n]);
        }
        return;
    }

    __shared__ short lds[(64 + 192) * 72];   // xT then wTs
    short* xT = lds;
    short* wTs = lds + 64 * 72;
    const int px0 = blockIdx.x * 64;

    #pragma unroll
    for (int r = 0; r < 16; ++r) {
        const int idx = r * 256 + t;          // 0..4095
        const int cin = idx >> 6, pxl = idx & 63;
        xT[pxl * 72 + cin] = f16s(x[(size_t)cin * NPIX + px0 + pxl]);
    }
    #pragma unroll
    for (int m = 0; m < 3; ++m) {
        const float* ws = (m == 0) ? wq : (m == 1) ? wk : wv;
        #pragma unroll
        for (int r = 0; r < 16; ++r) {
            const int idx = r * 256 + t;      // 0..4095
            const int k = idx >> 6, n = idx & 63;
            wTs[(m * 64 + n) * 72 + k] = f16s(ws[k * 64 + n]);
        }
    }
    __syncthreads();

    const int lane = t & 63;
    const int wid  = t >> 6;                  // M-tile (16 px)
    const int l15  = lane & 15;
    const int kg4  = lane >> 4;

    f32x4 acc[12];
    #pragma unroll
    for (int nt = 0; nt < 12; ++nt) acc[nt] = (f32x4){0.f, 0.f, 0.f, 0.f};

    #pragma unroll
    for (int ks = 0; ks < 2; ++ks) {
        const f16x8 a = *reinterpret_cast<const f16x8*>(
            &xT[(wid * 16 + l15) * 72 + ks * 32 + kg4 * 8]);
        #pragma unroll
        for (int nt = 0; nt < 12; ++nt) {
            const f16x8 b = *reinterpret_cast<const f16x8*>(
                &wTs[(nt * 16 + l15) * 72 + ks * 32 + kg4 * 8]);
            acc[nt] = __builtin_amdgcn_mfma_f32_16x16x32_f16(a, b, acc[nt], 0, 0, 0);
        }
    }

    #pragma unroll
    for (int nt = 0; nt < 12; ++nt) {
        unsigned int* dst = (nt < 4) ? qg : (nt < 8) ? kg : vg;
        const int dwb = (nt & 3) * 8 + (l15 >> 1);
        #pragma unroll
        for (int r = 0; r < 4; ++r) {
            const float val = acc[nt][r];
            const float par = __shfl_xor(val, 1, 64);
            if (!(lane & 1)) {
                const int opx = px0 + wid * 16 + kg4 * 4 + r;
                dst[(size_t)opx * 32 + dwb] = pack_f16(val, par);
            }
        }
    }
}

// one neighborhood step: packed-f16 dot (v_dot2_f32_f16) + packed-f16 PV
// accumulate. pf scaled by 1/16 (cancels in S division) to keep f16 acc safe.
#define NBR_STEP(HIDX)                                                        \
    {                                                                         \
        const int hidx_ = (HIDX);                                             \
        const uint4 ka = *reinterpret_cast<const uint4*>(kreg + hidx_ * 8);   \
        const uint4 k2 = *reinterpret_cast<const uint4*>(kreg + hidx_ * 8 + 4);\
        float da = FDOT2(u2h(ka.x), qv2[0], 0.f);                             \
        float db = FDOT2(u2h(ka.y), qv2[1], 0.f);                             \
        da = FDOT2(u2h(ka.z), qv2[2], da);                                    \
        db = FDOT2(u2h(ka.w), qv2[3], db);                                    \
        da = FDOT2(u2h(k2.x), qv2[4], da);                                    \
        db = FDOT2(u2h(k2.y), qv2[5], db);                                    \
        da = FDOT2(u2h(k2.z), qv2[6], da);                                    \
        db = FDOT2(u2h(k2.w), qv2[7], db);                                    \
        const float dot = da + db;                                            \
        const float m = sm[hidx_];                                            \
        const float pf = __expf(SCALE * dot * m) * 0.0625f;                   \
        S += pf;                                                              \
        const _Float16 pmh = (_Float16)(pf * m);                              \
        const f16x2 pm2 = {pmh, pmh};                                         \
        const uint4 va = *reinterpret_cast<const uint4*>(vreg + hidx_ * 8);   \
        const uint4 v2 = *reinterpret_cast<const uint4*>(vreg + hidx_ * 8 + 4);\
        acc2[0] = pm2 * u2h(va.x) + acc2[0];                                  \
        acc2[1] = pm2 * u2h(va.y) + acc2[1];                                  \
        acc2[2] = pm2 * u2h(va.z) + acc2[2];                                  \
        acc2[3] = pm2 * u2h(va.w) + acc2[3];                                  \
        acc2[4] = pm2 * u2h(v2.x) + acc2[4];                                  \
        acc2[5] = pm2 * u2h(v2.y) + acc2[5];                                  \
        acc2[6] = pm2 * u2h(v2.z) + acc2[6];                                  \
        acc2[7] = pm2 * u2h(v2.w) + acc2[7];                                  \
    }

// ---------------------------------------------------------------------------
// Kernel 2: tiled neighborhood attention + fused MFMA output projection.
// Structure = r10 (K AND V staged in LDS — r11 proved V staging load-bearing),
// inner loop = packed f16. Block 256: 8x4 px x 4 heads x 2 halves; grid 1152,
// XCD-swizzled; LDS 36.5 KB.
// ---------------------------------------------------------------------------
__global__ __launch_bounds__(256) void attn_proj(
    const unsigned int* __restrict__ qg,
    const unsigned int* __restrict__ kg,
    const unsigned int* __restrict__ vg,
    const float* __restrict__ sims,
    const short* __restrict__ wT,
    float* __restrict__ out)
{
    __shared__ unsigned int smem[8 * REG2 + NH];  // k[4][REG2], v[4][REG2], sims

    const int bid = blockIdx.x;
    const int tl = (bid & 7) * 144 + (bid >> 3);  // XCD swizzle (1152 = 8*144)
    const int ty = tl / 48, tx = tl - ty * 48;
    const int Y0 = ty * 8, X0 = tx * 4;
    int hy0 = Y0 - 3; hy0 = hy0 < 0 ? 0 : (hy0 > HH - HLY ? HH - HLY : hy0);
    int hx0 = X0 - 3; hx0 = hx0 < 0 ? 0 : (hx0 > WW - HLX ? WW - HLX : hx0);
    const int t = threadIdx.x;

    // ---- stage k,v halo: 140 px x 8 uint4 (64 ch) = 1120 units per tensor
    #pragma unroll
    for (int i = 0; i < 5; ++i) {
        const int idx = i * 256 + t;
        if (idx < NH * 8) {
            const int hidx = idx >> 3, u = idx & 7;
            const int r = hidx / HLX, c = hidx - r * HLX;
            const int np = (hy0 + r) * WW + hx0 + c;
            const int h = u >> 1, hf = u & 1;
            const size_t src = (size_t)np * 32 + u * 4;
            const uint4 kk = *reinterpret_cast<const uint4*>(kg + src);
            const uint4 vv = *reinterpret_cast<const uint4*>(vg + src);
            unsigned int* dk = smem + h * REG2 + hidx * 8 + hf * 4;
            *reinterpret_cast<uint4*>(dk) = kk;
            *reinterpret_cast<uint4*>(dk + 4 * REG2) = vv;
        }
    }
    if (t < NH) {
        const int r = t / HLX, c = t - r * HLX;
        const int np = (hy0 + r) * WW + hx0 + c;
        const int sbase = (Y0 >> 4) * 12 + (X0 >> 4);   // block-uniform
        reinterpret_cast<float*>(smem)[8 * REG2 + t] = sims[np * 144 + sbase];
    }
    __syncthreads();

    // ---- attention: thread = (pixel, head, neighbor-half)
    const int half = t & 1, hl = (t >> 1) & 1, p = (t >> 2) & 31, hp = t >> 7;
    const int h = hp * 2 + hl;
    const int py = p >> 2, pxq = p & 3;
    const int y = Y0 + py, xq = X0 + pxq;
    int sy = y - 3;  sy = sy < 0 ? 0 : (sy > HH - 7 ? HH - 7 : sy);
    int sx = xq - 3; sx = sx < 0 ? 0 : (sx > WW - 7 ? WW - 7 : sx);
    const int wbase = (sy - hy0) * HLX + (sx - hx0);

    f16x2 qv2[8];
    {
        const unsigned int* qp = qg + (size_t)(y * WW + xq) * 32 + h * 8;
        const uint4 a = *reinterpret_cast<const uint4*>(qp);
        const uint4 b = *reinterpret_cast<const uint4*>(qp + 4);
        qv2[0] = u2h(a.x); qv2[1] = u2h(a.y); qv2[2] = u2h(a.z); qv2[3] = u2h(a.w);
        qv2[4] = u2h(b.x); qv2[5] = u2h(b.y); qv2[6] = u2h(b.z); qv2[7] = u2h(b.w);
    }

    const unsigned int* kreg = smem + h * REG2;
    const unsigned int* vreg = smem + (4 + h) * REG2;
    const float* sm = reinterpret_cast<const float*>(smem + 8 * REG2);

    float S = 0.f;
    f16x2 acc2[8];
    #pragma unroll
    for (int d = 0; d < 8; ++d) acc2[d] = (f16x2){(_Float16)0.f, (_Float16)0.f};

    // neighbors nn = 2*i + half, i = 0..23 unconditional; tail nn=48 (half 0)
    #pragma unroll
    for (int i = 0; i < 24; ++i) {
        const int nn = 2 * i + half;
        const int ky = (nn * 37) >> 8;        // nn/7 for nn<56
        const int kx = nn - 7 * ky;
        NBR_STEP(wbase + ky * HLX + kx);
    }
    if (half == 0) {
        NBR_STEP(wbase + 6 * HLX + 6);        // nn = 48
    }

    // combine even/odd neighbor halves (adjacent lanes share (p,h))
    const float S2 = S + __shfl_xor(S, 1, 64);
    float lo[8], hi[8];
    #pragma unroll
    for (int j = 0; j < 8; ++j) {
        lo[j] = (float)acc2[j >> 1][j & 1];           // ch j
        hi[j] = (float)acc2[4 + (j >> 1)][j & 1];     // ch 8+j
    }
    #pragma unroll
    for (int j = 0; j < 8; ++j) {
        lo[j] += __shfl_xor(lo[j], 1, 64);
        hi[j] += __shfl_xor(hi[j], 1, 64);
    }
    const float inv = 1.f / S2;
    float o[8];
    #pragma unroll
    for (int j = 0; j < 8; ++j) o[j] = ((half == 0) ? lo[j] : hi[j]) * inv;

    // ---- fused projection: attn-out -> LDS (f16 A-tile), MFMA with wp
    __syncthreads();                           // all k/v/sims LDS reads done
    {
        // A_lds: [32 px][72 ch-pad] shorts, overlaps dead k region
        short* A_lds = reinterpret_cast<short*>(smem);
        const uint4 w4 = make_uint4(pack_f16(o[0], o[1]), pack_f16(o[2], o[3]),
                                    pack_f16(o[4], o[5]), pack_f16(o[6], o[7]));
        *reinterpret_cast<uint4*>(&A_lds[p * 72 + h * 16 + half * 8]) = w4;
    }
    __syncthreads();

    const short* A_lds = reinterpret_cast<const short*>(smem);
    const int lane = t & 63;
    const int w    = t >> 6;                   // wave id
    const int mt   = w & 1;                    // M-tile (16 px)
    const int np2  = w >> 1;                   // N-pair (2 x 16 couts)
    const int l15  = lane & 15;
    const int kg4  = lane >> 4;

    f16x8 afrag[2];
    #pragma unroll
    for (int ks = 0; ks < 2; ++ks)
        afrag[ks] = *reinterpret_cast<const f16x8*>(
            &A_lds[(mt * 16 + l15) * 72 + ks * 32 + kg4 * 8]);

    #pragma unroll
    for (int nt2 = 0; nt2 < 2; ++nt2) {
        const int nt = np2 * 2 + nt2;
        const int n = nt * 16 + l15;
        f32x4 pacc = (f32x4){0.f, 0.f, 0.f, 0.f};
        #pragma unroll
        for (int ks = 0; ks < 2; ++ks) {
            const f16x8 b = *reinterpret_cast<const f16x8*>(
                &wT[(192 + n) * 64 + ks * 32 + kg4 * 8]);
            pacc = __builtin_amdgcn_mfma_f32_16x16x32_f16(afrag[ks], b, pacc, 0, 0, 0);
        }
        const int pr = mt * 16 + kg4 * 4;      // 4 consecutive tile pixels
        const int gy = Y0 + (pr >> 2);         // = one tile row
        *reinterpret_cast<float4*>(out + (size_t)n * NPIX + gy * WW + X0) =
            make_float4(pacc[0], pacc[1], pacc[2], pacc[3]);
    }
}

// ---------------------------------------------------------------------------
extern "C" void kernel_launch(void* const* d_in, const int* in_sizes, int n_in,
                              void* d_out, int out_size, void* d_ws, size_t ws_size,
                              hipStream_t stream)
{
    const float* x    = (const float*)d_in[0];
    const float* sims = (const float*)d_in[1];
    const float* wq   = (const float*)d_in[2];
    const float* wk   = (const float*)d_in[3];
    const float* wv   = (const float*)d_in[4];
    const float* wp   = (const float*)d_in[5];
    float* out = (float*)d_out;

    unsigned int* qg = (unsigned int*)d_ws;            // f16x2 [NPIX][32]
    unsigned int* kg = qg + (size_t)NPIX * 32;
    unsigned int* vg = kg + (size_t)NPIX * 32;
    short* wT = (short*)(vg + (size_t)NPIX * 32);      // f16 [256][64]

    qkv_mfma<<<NPIX / 64 + 1, 256, 0, stream>>>(x, wq, wk, wv, wp, qg, kg, vg, wT);
    attn_proj<<<1152, 256, 0, stream>>>(qg, kg, vg, sims, wT, out);
}